// Round 2
// baseline (6173.314 us; speedup 1.0000x reference)
//
#include <hip/hip_runtime.h>
#include <stdint.h>
#include <stddef.h>

// ---------------------------------------------------------------------------
// BiLSTM seq2seq (Bahdanau attention) on MI355X.
// B=32, T_src=T_tgt=64, E=512, H=512 (enc dir), dec hidden 2H=1024, V=32000.
// Inputs: bf16 storage (harness casts float inputs to bf16). OUTPUT: fp32
// (reference returns fp32 log_softmax). Accumulate fp32 everywhere.
// ---------------------------------------------------------------------------

using u16 = unsigned short;
using u32 = unsigned int;
using short8 = __attribute__((ext_vector_type(8))) short;  // 8 bf16 (4 VGPRs)
using f32x4  = __attribute__((ext_vector_type(4))) float;  // MFMA acc

#define DEVI __device__ __forceinline__

DEVI float bf2f(u16 u){ union{u32 i; float f;} v; v.i = ((u32)u)<<16; return v.f; }
DEVI u16 f2bf(float f){ union{float f; u32 i;} v; v.f = f;
  u32 r = (v.i + 0x7fffu + ((v.i>>16)&1u)) >> 16; return (u16)r; }
DEVI float sigf(float x){ x = fminf(fmaxf(x,-30.f),30.f); return 1.f/(1.f+__expf(-x)); }
DEVI float tanh_f(float x){ float ax = fminf(fabsf(x),15.f);
  float e = __expf(2.f*ax); float t = (e-1.f)/(e+1.f); return x<0.f? -t : t; }

DEVI f32x4 mfma16(short8 a, short8 b, f32x4 c){
  return __builtin_amdgcn_mfma_f32_16x16x32_bf16(a,b,c,0,0,0);
}
DEVI short8 ld8(const u16* p){ return *(const short8*)p; }

DEVI void storeC(float* C, size_t i, float v){ C[i]=v; }
DEVI void storeC(u16*   C, size_t i, float v){ C[i]=f2bf(v); }

// ---------------------------------------------------------------------------
// Embedding gather: emb_src[t*32+b] = enc_emb[inp[b][t]], same for decoder.
// grid (2048, 2), block 64 (one uint4 = 8 bf16 per thread, row = 64 uint4).
// ---------------------------------------------------------------------------
__global__ void gather_emb(const int* __restrict__ inp, const int* __restrict__ tar,
                           const u16* __restrict__ enc_emb, const u16* __restrict__ dec_emb,
                           u16* __restrict__ emb_src, u16* __restrict__ dec_e)
{
  int row = blockIdx.x;            // t*32 + b
  int t = row >> 5, b = row & 31;
  int d = blockIdx.y;
  int idx = (d ? tar : inp)[b*64 + t];
  const uint4* src = (const uint4*)((d ? dec_emb : enc_emb) + (size_t)idx*512);
  uint4*       dst = (uint4*)((d ? dec_e : emb_src) + (size_t)row*512);
  dst[threadIdx.x] = src[threadIdx.x];
}

__global__ void zero_u16k(u16* __restrict__ p, int n){
  int i = blockIdx.x*blockDim.x + threadIdx.x; if(i<n) p[i]=0;
}

// ---------------------------------------------------------------------------
// Generic MFMA GEMM: C[M,N] = act(A[M,K] * W[N,K]^T + bias). 64x64 tile,
// 4 waves (2x2), 2x2 16x16 frags per wave, direct-global frag loads (no LDS).
// Dims: M%64==0, N%64==0, K%32==0.
// ---------------------------------------------------------------------------
template<int BIAS, int RELU, typename OutT>
__global__ void __launch_bounds__(256) gemm_bt(
  const u16* __restrict__ A, int lda,
  const u16* __restrict__ W, int ldw,
  const u16* __restrict__ bias,
  OutT* __restrict__ C, int ldc, int K)
{
  int lane = threadIdx.x & 63, w = threadIdx.x >> 6;
  int wm = w >> 1, wn = w & 1;
  int bm = blockIdx.y*64 + wm*32, bn = blockIdx.x*64 + wn*32;
  int q = lane >> 4, col = lane & 15;
  const u16* a0p = A + (size_t)(bm + col)*lda + q*8;
  const u16* a1p = a0p + (size_t)16*lda;
  const u16* b0p = W + (size_t)(bn + col)*ldw + q*8;
  const u16* b1p = b0p + (size_t)16*ldw;
  f32x4 z = {0.f,0.f,0.f,0.f};
  f32x4 acc[2][2] = {{z,z},{z,z}};
  for(int k=0;k<K;k+=32){
    short8 a0 = ld8(a0p + k);
    short8 a1 = ld8(a1p + k);
    short8 b0 = ld8(b0p + k);
    short8 b1 = ld8(b1p + k);
    acc[0][0] = mfma16(a0,b0,acc[0][0]);
    acc[0][1] = mfma16(a0,b1,acc[0][1]);
    acc[1][0] = mfma16(a1,b0,acc[1][0]);
    acc[1][1] = mfma16(a1,b1,acc[1][1]);
  }
  #pragma unroll
  for(int fm=0; fm<2; fm++){
    #pragma unroll
    for(int fn=0; fn<2; fn++){
      int colg = bn + fn*16 + col;
      float bia = BIAS ? bf2f(bias[colg]) : 0.f;
      #pragma unroll
      for(int r=0;r<4;r++){
        int rowg = bm + fm*16 + q*4 + r;   // D: row=(lane>>4)*4+reg, col=lane&15
        float x = acc[fm][fn][r] + bia;
        if(RELU) x = fmaxf(x, 0.f);
        storeC(C, (size_t)rowg*ldc + colg, x);
      }
    }
  }
}

// ---------------------------------------------------------------------------
// Small-M GEMM (M=32): C[32,N] = A[32,K] * W[N,K]^T, fp32 out.
// grid N/64, block 256 (4 waves, each one 16-col frag, 2 m-frags).
// Used for hWa1 = h @ Wa1^T each decoder step.
// ---------------------------------------------------------------------------
__global__ void __launch_bounds__(256) gemm_m32(
  const u16* __restrict__ A, int lda,
  const u16* __restrict__ W, int ldw,
  float* __restrict__ C, int ldc, int K)
{
  int lane = threadIdx.x & 63, w = threadIdx.x >> 6;
  int bn = blockIdx.x*64 + w*16;
  int q = lane>>4, col = lane&15;
  const u16* ap = A + (size_t)col*lda + q*8;
  const u16* wp = W + (size_t)(bn+col)*ldw + q*8;
  f32x4 z = {0.f,0.f,0.f,0.f};
  f32x4 acc0=z, acc1=z;
  for(int k=0;k<K;k+=32){
    short8 a0 = ld8(ap + k);
    short8 a1 = ld8(ap + (size_t)16*lda + k);
    short8 b  = ld8(wp + k);
    acc0 = mfma16(a0,b,acc0); acc1 = mfma16(a1,b,acc1);
  }
  #pragma unroll
  for(int r=0;r<4;r++){
    C[(size_t)(q*4 + r)*ldc + bn + col]      = acc0[r];
    C[(size_t)(16 + q*4 + r)*ldc + bn + col] = acc1[r];
  }
}

// ---------------------------------------------------------------------------
// Encoder LSTM cell step (both directions). grid (32 unit-chunks, 2 dirs),
// block 256 = 4 waves, wave w = gate w (PyTorch order i,f,g,o).
// Block owns 16 hidden units x all 32 batches -> pointwise fused in epilogue.
// h ping-pongs between two bf16 buffers (no cross-block read/write race).
// ---------------------------------------------------------------------------
__global__ void __launch_bounds__(256) enc_cell(
  const u16* __restrict__ Whh_f, const u16* __restrict__ Whh_b,
  const u16* __restrict__ Xf, const u16* __restrict__ Xb,   // [2048,2048] bf16 (x@Wih^T+b)
  const u16* __restrict__ hin, u16* __restrict__ hout,      // [2][32][512] bf16
  float* __restrict__ c_enc,                                // [2][32][512] fp32
  u16* __restrict__ enc_out,                                // [64][32][1024] bf16
  u16* __restrict__ A0h, float* __restrict__ c_buf,         // decoder init (s==63)
  int s)
{
  int tid = threadIdx.x, lane = tid&63, w = tid>>6;   // w = gate
  int dir = blockIdx.y, j0 = blockIdx.x*16;
  int q = lane>>4, col = lane&15;
  const u16* W  = dir ? Whh_b : Whh_f;
  const u16* Xp = dir ? Xb : Xf;
  int t = dir ? 63 - s : s;
  int n = w*512 + j0 + col;
  const u16* wp = W + (size_t)n*512 + q*8;
  const u16* ap = hin + (size_t)(dir*32 + col)*512 + q*8;
  f32x4 z = {0.f,0.f,0.f,0.f};
  f32x4 acc0=z, acc1=z;
  for(int kk=0; kk<512; kk+=32){
    short8 a0 = ld8(ap + kk);
    short8 a1 = ld8(ap + 16*512 + kk);
    short8 b  = ld8(wp + kk);
    acc0 = mfma16(a0,b,acc0); acc1 = mfma16(a1,b,acc1);
  }
  __shared__ float gl[4][32][16];
  #pragma unroll
  for(int r=0;r<4;r++){
    gl[w][q*4+r][col]      = acc0[r];
    gl[w][16+q*4+r][col]   = acc1[r];
  }
  __syncthreads();
  for(int i = tid; i < 512; i += 256){
    int b_ = i>>4, jl = i&15, j = j0 + jl;
    size_t xrow = (size_t)(t*32 + b_)*2048;
    float gi = gl[0][b_][jl] + bf2f(Xp[xrow + j]);
    float gf = gl[1][b_][jl] + bf2f(Xp[xrow + 512 + j]);
    float gg = gl[2][b_][jl] + bf2f(Xp[xrow + 1024 + j]);
    float go = gl[3][b_][jl] + bf2f(Xp[xrow + 1536 + j]);
    int ci = (dir*32 + b_)*512 + j;
    float c = s ? c_enc[ci] : 0.f;
    float cn = sigf(gf)*c + sigf(gi)*tanh_f(gg);
    float hn = sigf(go)*tanh_f(cn);
    c_enc[ci] = cn;
    u16 hb = f2bf(hn);
    hout[(size_t)(dir*32 + b_)*512 + j] = hb;
    enc_out[(size_t)(t*32 + b_)*1024 + dir*512 + j] = hb;
    if(s==63){  // decoder init: h0 = concat(hf,hb) (bf16 in A-buffer), c0 fp32
      A0h[b_*2048 + 1024 + dir*512 + j] = hb;
      c_buf[b_*1024 + dir*512 + j] = cn;
    }
  }
}

// ---------------------------------------------------------------------------
// Attention for one decoder step: score -> softmax over T_src -> cvec.
// grid 32 (batch), block 1024. energy = tanh(hWa1[b] + encWa2[t,b]); both
// GEMM halves precomputed (encWa2 is step-invariant).
// ---------------------------------------------------------------------------
__global__ void __launch_bounds__(1024) att_kernel(
  const float* __restrict__ hWa1,    // [32,1024] fp32
  const u16* __restrict__ encWa2,    // [2048,1024] bf16
  const u16* __restrict__ va,        // [1024] bf16
  const u16* __restrict__ enc_out,   // [2048,1024] bf16
  u16* __restrict__ Acur)            // write cvec -> Acur[b*2048 + 0..1023]
{
  int b = blockIdx.x, tid = threadIdx.x;
  __shared__ float e_s[1024], va_s[1024], sc_s[64], al_s[64];
  e_s[tid]  = hWa1[b*1024 + tid];
  va_s[tid] = bf2f(va[tid]);
  __syncthreads();
  // scores: 16 lanes per t_src
  int t16 = tid >> 4, l16 = tid & 15;
  const u16* erow = encWa2 + (size_t)(t16*32 + b)*1024;
  float pacc = 0.f;
  for(int j = l16; j < 1024; j += 16)
    pacc += tanh_f(e_s[j] + bf2f(erow[j])) * va_s[j];
  #pragma unroll
  for(int off=8; off; off>>=1) pacc += __shfl_down(pacc, off, 16);
  if(l16==0) sc_s[t16] = pacc;
  __syncthreads();
  if(tid < 64){
    float sv = sc_s[tid];
    float m = sv;
    #pragma unroll
    for(int off=32; off; off>>=1) m = fmaxf(m, __shfl_xor(m, off, 64));
    float e = __expf(sv - m);
    float ssum = e;
    #pragma unroll
    for(int off=32; off; off>>=1) ssum += __shfl_xor(ssum, off, 64);
    al_s[tid] = e / ssum;
  }
  __syncthreads();
  float cv = 0.f;
  for(int tt=0; tt<64; tt++)
    cv += al_s[tt] * bf2f(enc_out[(size_t)(tt*32 + b)*1024 + tid]);
  Acur[b*2048 + tid] = f2bf(cv);
}

// ---------------------------------------------------------------------------
// Decoder LSTM cell step: gates = Xd[t] + cvec@Wih_d2^T + h@Whh_d^T, fused
// pointwise. grid 64 (unit chunks of 16), block 512 = 8 waves:
// wave = (gate g=w&3, K-half kh=w>>2). kh=0: A cvec-half vs Wih_d[:,512:1536];
// kh=1: A h-half vs Whh_d. Reads Acur, writes h into Anext (ping-pong).
// ---------------------------------------------------------------------------
__global__ void __launch_bounds__(512) dec_cell(
  const u16* __restrict__ A,         // [32,2048] bf16: cvec|h (current)
  const u16* __restrict__ Wih_d,     // [4096,1536]
  const u16* __restrict__ Whh_d,     // [4096,1024]
  const u16* __restrict__ Xd,        // [2048,4096] bf16 (x@Wih_d1^T + b_d)
  float* __restrict__ c_buf,         // [32,1024]
  u16* __restrict__ Anext,           // write h half
  u16* __restrict__ hs,              // [32*64,1024] bf16, row = b*64+t
  int t)
{
  int tid = threadIdx.x, lane = tid & 63, w = tid >> 6;
  int g = w & 3, kh = w >> 2;
  int j0 = blockIdx.x * 16;
  int q = lane >> 4, col = lane & 15;
  int n = g*1024 + j0 + col;
  const u16* wp = kh ? (Whh_d + (size_t)n*1024 + q*8)
                     : (Wih_d + (size_t)n*1536 + 512 + q*8);
  const u16* ap = A + (size_t)col*2048 + kh*1024 + q*8;
  f32x4 z = {0.f,0.f,0.f,0.f};
  f32x4 acc0=z, acc1=z;
  for(int kk=0; kk<1024; kk+=32){
    short8 a0 = ld8(ap + kk);
    short8 a1 = ld8(ap + 16*2048 + kk);
    short8 b  = ld8(wp + kk);
    acc0 = mfma16(a0,b,acc0); acc1 = mfma16(a1,b,acc1);
  }
  __shared__ float gp[2][4][32][16];
  #pragma unroll
  for(int r=0;r<4;r++){
    gp[kh][g][q*4+r][col]    = acc0[r];
    gp[kh][g][16+q*4+r][col] = acc1[r];
  }
  __syncthreads();
  {
    int b_ = tid >> 4, jl = tid & 15, j = j0 + jl;
    size_t xrow = (size_t)(t*32 + b_)*4096;
    float gi = gp[0][0][b_][jl] + gp[1][0][b_][jl] + bf2f(Xd[xrow + j]);
    float gf = gp[0][1][b_][jl] + gp[1][1][b_][jl] + bf2f(Xd[xrow + 1024 + j]);
    float gg = gp[0][2][b_][jl] + gp[1][2][b_][jl] + bf2f(Xd[xrow + 2048 + j]);
    float go = gp[0][3][b_][jl] + gp[1][3][b_][jl] + bf2f(Xd[xrow + 3072 + j]);
    float c = c_buf[b_*1024 + j];
    float cn = sigf(gf)*c + sigf(gi)*tanh_f(gg);
    float hn = sigf(go)*tanh_f(cn);
    c_buf[b_*1024 + j] = cn;
    u16 hb = f2bf(hn);
    Anext[b_*2048 + 1024 + j] = hb;
    hs[(size_t)(b_*64 + t)*1024 + j] = hb;
  }
}

// ---------------------------------------------------------------------------
// In-place row-wise log_softmax over V=32000 FP32 (after relu'd logits).
// grid 2048 (rows), block 256. float4 vector access, 8000 float4 per row.
// ---------------------------------------------------------------------------
__global__ void __launch_bounds__(256) log_softmax_rows(float* __restrict__ out)
{
  int r = blockIdx.x, tid = threadIdx.x;
  float* row = out + (size_t)r*32000;
  const float4* row4 = (const float4*)row;
  __shared__ float rbuf[16];
  // pass 1: max
  float m = -1e30f;
  for(int c = tid; c < 8000; c += 256){
    float4 u = row4[c];
    m = fmaxf(m, fmaxf(fmaxf(u.x,u.y), fmaxf(u.z,u.w)));
  }
  #pragma unroll
  for(int off=32; off; off>>=1) m = fmaxf(m, __shfl_down(m, off, 64));
  if((tid&63)==0) rbuf[tid>>6] = m;
  __syncthreads();
  if(tid==0) rbuf[8] = fmaxf(fmaxf(rbuf[0],rbuf[1]), fmaxf(rbuf[2],rbuf[3]));
  __syncthreads();
  float M = rbuf[8];
  // pass 2: sum exp
  float s = 0.f;
  for(int c = tid; c < 8000; c += 256){
    float4 u = row4[c];
    s += __expf(u.x-M) + __expf(u.y-M) + __expf(u.z-M) + __expf(u.w-M);
  }
  #pragma unroll
  for(int off=32; off; off>>=1) s += __shfl_down(s, off, 64);
  if((tid&63)==0) rbuf[4 + (tid>>6)] = s;
  __syncthreads();
  if(tid==0) rbuf[9] = M + logf(rbuf[4]+rbuf[5]+rbuf[6]+rbuf[7]);
  __syncthreads();
  float L = rbuf[9];
  // pass 3: rewrite
  float4* row4w = (float4*)row;
  for(int c = tid; c < 8000; c += 256){
    float4 u = row4[c];
    u.x -= L; u.y -= L; u.z -= L; u.w -= L;
    row4w[c] = u;
  }
}

// ---------------------------------------------------------------------------
extern "C" void kernel_launch(void* const* d_in, const int* in_sizes, int n_in,
                              void* d_out, int out_size, void* d_ws, size_t ws_size,
                              hipStream_t stream)
{
  (void)in_sizes; (void)n_in; (void)out_size; (void)ws_size;
  const int* inp     = (const int*)d_in[0];
  const int* tar     = (const int*)d_in[1];
  const u16* enc_emb = (const u16*)d_in[2];
  const u16* dec_emb = (const u16*)d_in[3];
  const u16* Wih_f   = (const u16*)d_in[4];
  const u16* Whh_f   = (const u16*)d_in[5];
  const u16* b_f     = (const u16*)d_in[6];
  const u16* Wih_b   = (const u16*)d_in[7];
  const u16* Whh_b   = (const u16*)d_in[8];
  const u16* b_b     = (const u16*)d_in[9];
  const u16* Wa      = (const u16*)d_in[10];
  const u16* va      = (const u16*)d_in[11];
  const u16* Wih_d   = (const u16*)d_in[12];
  const u16* Whh_d   = (const u16*)d_in[13];
  const u16* b_d     = (const u16*)d_in[14];
  const u16* Wout    = (const u16*)d_in[15];
  const u16* bout    = (const u16*)d_in[16];

  // workspace carve (all 256B aligned); total ~49 MB
  char* p = (char*)d_ws;
  auto carve = [&](size_t bytes)->char*{
    char* r = p; p += (bytes + 255) & ~(size_t)255; return r; };
  u16*   emb_src = (u16*)  carve(2048ull*512*2);
  u16*   dec_e   = (u16*)  carve(2048ull*512*2);
  u16*   Xf      = (u16*)  carve(2048ull*2048*2);
  u16*   Xb      = (u16*)  carve(2048ull*2048*2);
  u16*   Xd      = (u16*)  carve(2048ull*4096*2);
  u16*   enc_out = (u16*)  carve(2048ull*1024*2);
  u16*   encWa2  = (u16*)  carve(2048ull*1024*2);
  u16*   h_enc   = (u16*)  carve(2ull*2*32*512*2);   // 2 ping-pong buffers
  float* c_enc   = (float*)carve(2ull*32*512*4);
  u16*   A_buf   = (u16*)  carve(2ull*32*2048*2);    // 2 ping-pong (cvec|h)
  float* c_buf   = (float*)carve(32ull*1024*4);
  float* hWa1    = (float*)carve(32ull*1024*4);
  u16*   hs      = (u16*)  carve(2048ull*1024*2);

  // --- embeddings + init ---
  gather_emb<<<dim3(2048,2),64,0,stream>>>(inp,tar,enc_emb,dec_emb,emb_src,dec_e);
  zero_u16k<<<128,256,0,stream>>>(h_enc, 2*32*512);

  // --- input-side gate precompute GEMMs (time-parallel) ---
  gemm_bt<1,0,u16><<<dim3(32,32),256,0,stream>>>(emb_src,512, Wih_f,512,  b_f, Xf,2048, 512);
  gemm_bt<1,0,u16><<<dim3(32,32),256,0,stream>>>(emb_src,512, Wih_b,512,  b_b, Xb,2048, 512);
  gemm_bt<1,0,u16><<<dim3(64,32),256,0,stream>>>(dec_e,  512, Wih_d,1536, b_d, Xd,4096, 512);

  // --- encoder BiLSTM recurrence (64 steps, both dirs per launch) ---
  for(int s=0;s<64;s++){
    u16* hin  = h_enc + (s&1)*2*32*512;
    u16* hout = h_enc + ((s+1)&1)*2*32*512;
    enc_cell<<<dim3(32,2),256,0,stream>>>(Whh_f,Whh_b, Xf,Xb, hin,hout,
                                          c_enc, enc_out, A_buf, c_buf, s);
  }

  // --- decoder-step-invariant attention half: enc_out @ Wa2^T ---
  gemm_bt<0,0,u16><<<dim3(16,32),256,0,stream>>>(enc_out,1024, Wa+1024,2048,
                                                 nullptr, encWa2,1024, 1024);

  // --- decoder (64 steps x 3 kernels) ---
  for(int t=0;t<64;t++){
    u16* Acur  = A_buf + (t&1)*32*2048;
    u16* Anext = A_buf + ((t+1)&1)*32*2048;
    gemm_m32<<<16,256,0,stream>>>(Acur+1024, 2048, Wa, 2048, hWa1, 1024, 1024);
    att_kernel<<<32,1024,0,stream>>>(hWa1, encWa2, va, enc_out, Acur);
    dec_cell<<<64,512,0,stream>>>(Acur, Wih_d, Whh_d, Xd, c_buf, Anext, hs, t);
  }

  // --- output projection + relu (FP32 logits into d_out), then log_softmax ---
  gemm_bt<1,1,float><<<dim3(500,32),256,0,stream>>>(hs,1024, Wout,1024, bout,
                                                    (float*)d_out,32000, 1024);
  log_softmax_rows<<<2048,256,0,stream>>>((float*)d_out);
}